// Round 5
// baseline (1283.554 us; speedup 1.0000x reference)
//
#include <hip/hip_runtime.h>
#include <math.h>

#define NN 50000
#define NE 640000
#define H 128
#define EPB 32        // edges per block
#define NPB 32        // nodes per block
#define ZB 296        // LDS stride (bf16) for z rows (592 B)
#define BB 136        // LDS stride (bf16) for 128-wide buffers (272 B)
#define KP1 288       // padded K for layer 1 (280 -> 288)
#define NZB 264       // LDS stride (bf16) for node 256-wide input (528 B)

typedef __attribute__((ext_vector_type(8))) unsigned short u16x8;
typedef __attribute__((ext_vector_type(8))) __bf16 bf16x8;
typedef __attribute__((ext_vector_type(2))) __bf16 bf16x2;
typedef __attribute__((ext_vector_type(4))) float f32x4;

__device__ __forceinline__ float silu_f(float v) {
    return v / (1.0f + __expf(-v));
}

__device__ __forceinline__ unsigned short f2bf(float f) {
    unsigned int u = __builtin_bit_cast(unsigned int, f);
    u += 0x7FFFu + ((u >> 16) & 1u);   // RNE
    return (unsigned short)(u >> 16);
}

__device__ __forceinline__ float bf2f(unsigned short s) {
    unsigned int u = ((unsigned int)s) << 16;
    return __builtin_bit_cast(float, u);
}

__device__ __forceinline__ unsigned int pkbf(float lo, float hi) {
#if __has_builtin(__builtin_amdgcn_cvt_pk_bf16_f32)
    bf16x2 v = __builtin_amdgcn_cvt_pk_bf16_f32(lo, hi);
    unsigned int r; __builtin_memcpy(&r, &v, 4); return r;
#else
    return (unsigned int)f2bf(lo) | ((unsigned int)f2bf(hi) << 16);
#endif
}

__device__ __forceinline__ f32x4 mfma16(u16x8 a, u16x8 b, f32x4 c) {
    return __builtin_amdgcn_mfma_f32_16x16x32_bf16(
        __builtin_bit_cast(bf16x8, a), __builtin_bit_cast(bf16x8, b), c, 0, 0, 0);
}

// Transposed-role GEMM: D = W^T (A) x in^T (B); lane holds features
// F+rt*16+quad*4..+3 for edges ci*16+r16. Epilogue silu -> bf16 LDS write.
template<int KT, int INSTR, bool SYNC_BEFORE_EPI>
__device__ __forceinline__ void layer_mfma(
    const unsigned short* __restrict__ inbuf,
    const unsigned short* __restrict__ wt,
    const float* __restrict__ bias,
    unsigned short* __restrict__ outbuf,
    int wv, int quad, int r16)
{
    f32x4 acc[2][2] = {};
    const int F = wv * 32;
    #pragma unroll
    for (int ks = 0; ks < KT / 32; ks++) {
        int ko = ks * 32 + quad * 8;
        u16x8 b0 = *(const u16x8*)(inbuf + r16 * INSTR + ko);
        u16x8 b1 = *(const u16x8*)(inbuf + (16 + r16) * INSTR + ko);
        u16x8 a0 = *(const u16x8*)(wt + (size_t)(F + r16) * KT + ko);
        u16x8 a1 = *(const u16x8*)(wt + (size_t)(F + 16 + r16) * KT + ko);
        acc[0][0] = mfma16(a0, b0, acc[0][0]);
        acc[0][1] = mfma16(a0, b1, acc[0][1]);
        acc[1][0] = mfma16(a1, b0, acc[1][0]);
        acc[1][1] = mfma16(a1, b1, acc[1][1]);
    }
    if (SYNC_BEFORE_EPI) __syncthreads();
    #pragma unroll
    for (int rt = 0; rt < 2; rt++) {
        int f0 = F + rt * 16 + quad * 4;
        float4 bv = *(const float4*)(bias + f0);
        #pragma unroll
        for (int ci = 0; ci < 2; ci++) {
            int e = ci * 16 + r16;
            float s0 = silu_f(acc[rt][ci][0] + bv.x);
            float s1 = silu_f(acc[rt][ci][1] + bv.y);
            float s2 = silu_f(acc[rt][ci][2] + bv.z);
            float s3 = silu_f(acc[rt][ci][3] + bv.w);
            uint2 p = { pkbf(s0, s1), pkbf(s2, s3) };
            *(uint2*)(outbuf + e * BB + f0) = p;
        }
    }
}

// ---------------- weight conversion: fp32 [k][n] -> bf16 [n][k] -------------
__global__ __launch_bounds__(256) void convert_weights(
    const float* __restrict__ We1, const float* __restrict__ We2,
    const float* __restrict__ Wx1, const float* __restrict__ Wn1,
    const float* __restrict__ Wn2,
    unsigned short* __restrict__ w1t, unsigned short* __restrict__ w2t,
    unsigned short* __restrict__ wx1t, unsigned short* __restrict__ wn1t,
    unsigned short* __restrict__ wn2t)
{
    int i = blockIdx.x * 256 + threadIdx.x;
    const int S1 = 128 * KP1;
    const int S2 = 128 * 128;
    const int S3 = 128 * 256;
    if (i < S1) {
        int n = i / KP1, k = i % KP1;
        w1t[i] = (k < 280) ? f2bf(We1[k * H + n]) : (unsigned short)0;
    } else if (i < S1 + S2) {
        int j = i - S1; int n = j / H, k = j % H;
        w2t[j] = f2bf(We2[k * H + n]);
    } else if (i < S1 + 2 * S2) {
        int j = i - S1 - S2; int n = j / H, k = j % H;
        wx1t[j] = f2bf(Wx1[k * H + n]);
    } else if (i < S1 + 2 * S2 + S3) {
        int j = i - S1 - 2 * S2; int n = j / 256, k = j % 256;
        wn1t[j] = f2bf(Wn1[k * H + n]);
    } else if (i < S1 + 3 * S2 + S3) {
        int j = i - S1 - 2 * S2 - S3; int n = j / H, k = j % H;
        wn2t[j] = f2bf(Wn2[k * H + n]);
    }
}

__global__ __launch_bounds__(256) void zero_kernel(float4* __restrict__ p, int n4) {
    int i = blockIdx.x * 256 + threadIdx.x;
    if (i < n4) p[i] = make_float4(0.f, 0.f, 0.f, 0.f);
}

// ---------------- edge kernel -----------------------------------------------
__global__ __launch_bounds__(256, 4) void edge_kernel(
    const float* __restrict__ h, const float* __restrict__ x,
    const int* __restrict__ ei, const float* __restrict__ edge_attr,
    const unsigned short* __restrict__ w1t, const float* __restrict__ be1,
    const unsigned short* __restrict__ w2t, const float* __restrict__ be2,
    const float* __restrict__ Winf, const float* __restrict__ binf,
    const unsigned short* __restrict__ wx1t, const float* __restrict__ bx1,
    const float* __restrict__ Wx2,
    float* __restrict__ mi, float* __restrict__ dx)
{
    __shared__ unsigned short zs[EPB * ZB];   // z input; aliased as m1 after L1
    __shared__ unsigned short m2[EPB * BB];   // mij (bf16, coord-layer input)
    __shared__ float relx_s[EPB][3];
    __shared__ float eij_s[EPB];
    __shared__ float epart[4][EPB];
    __shared__ float xpart[4][EPB];
    __shared__ int dst_s[EPB];
    __shared__ int src_s[EPB];
    __shared__ float winf_s[H];
    __shared__ float wx2_s[H];

    unsigned short* m1 = zs;   // alias: zs dead after layer-1 K-loop (+barrier)

    const int t = threadIdx.x;
    const int e0 = blockIdx.x * EPB;

    if (t < EPB) {
        src_s[t] = ei[e0 + t];
        dst_s[t] = ei[NE + e0 + t];
    }
    if (t >= 128 && t < 256) {
        winf_s[t - 128] = Winf[t - 128];
        wx2_s[t - 128] = Wx2[t - 128];
    }
    __syncthreads();                                               // A

    // Gather h[dst] -> z[0:128], h[src] -> z[128:256]; 8 lanes/edge.
    {
        int e = t >> 3, l = t & 7;
        int s = src_s[e], d = dst_s[e];
        const float4* hd = (const float4*)(h + (size_t)d * H);
        const float4* hs = (const float4*)(h + (size_t)s * H);
        unsigned short* zr = zs + e * ZB;
        float4 v0 = hd[l * 4 + 0], v1 = hd[l * 4 + 1];
        float4 v2 = hd[l * 4 + 2], v3 = hd[l * 4 + 3];
        uint4 p0 = { pkbf(v0.x, v0.y), pkbf(v0.z, v0.w), pkbf(v1.x, v1.y), pkbf(v1.z, v1.w) };
        uint4 p1 = { pkbf(v2.x, v2.y), pkbf(v2.z, v2.w), pkbf(v3.x, v3.y), pkbf(v3.z, v3.w) };
        *(uint4*)(zr + l * 16) = p0;
        *(uint4*)(zr + l * 16 + 8) = p1;
        float4 w0 = hs[l * 4 + 0], w1 = hs[l * 4 + 1];
        float4 w2 = hs[l * 4 + 2], w3 = hs[l * 4 + 3];
        uint4 q0 = { pkbf(w0.x, w0.y), pkbf(w0.z, w0.w), pkbf(w1.x, w1.y), pkbf(w1.z, w1.w) };
        uint4 q1 = { pkbf(w2.x, w2.y), pkbf(w2.z, w2.w), pkbf(w3.x, w3.y), pkbf(w3.z, w3.w) };
        *(uint4*)(zr + 128 + l * 16) = q0;
        *(uint4*)(zr + 128 + l * 16 + 8) = q1;
    }
    // Geometry + gaussians + edge_attr + pad; 1 thread/edge.
    if (t < EPB) {
        int s = src_s[t], d = dst_s[t];
        float rx = x[d * 3 + 0] - x[s * 3 + 0];
        float ry = x[d * 3 + 1] - x[s * 3 + 1];
        float rz = x[d * 3 + 2] - x[s * 3 + 2];
        float d2 = rx * rx + ry * ry + rz * rz;
        float dd = sqrtf(d2 + 1e-8f);
        float inv = 1.0f / (dd + 1.0f);
        relx_s[t][0] = rx * inv;
        relx_s[t][1] = ry * inv;
        relx_s[t][2] = rz * inv;
        const float step = 10.0f / 19.0f;
        const float coeff = -0.5f / (step * step);
        unsigned short* zr = zs + t * ZB;
        #pragma unroll
        for (int g = 0; g < 20; g++) {
            float df = dd - step * (float)g;
            zr[256 + g] = f2bf(__expf(coeff * df * df));
        }
        #pragma unroll
        for (int j = 0; j < 4; j++)
            zr[276 + j] = f2bf(edge_attr[(size_t)(e0 + t) * 4 + j]);
        #pragma unroll
        for (int j = 280; j < ZB; j++) zr[j] = 0;
    }
    __syncthreads();                                               // B

    const int wv = t >> 6, lane = t & 63;
    const int quad = lane >> 4, r16 = lane & 15;
    const int F = wv * 32;

    // Layer 1: (z @ We1)^T -> silu -> m1 (aliases zs; barrier C inside)
    layer_mfma<KP1, ZB, true>(zs, w1t, be1, m1, wv, quad, r16);
    __syncthreads();                                               // D

    // Layer 2: mij. Keep silu outputs in regs; also partial eij dot.
    float sil[2][2][4];
    {
        f32x4 acc[2][2] = {};
        #pragma unroll
        for (int ks = 0; ks < H / 32; ks++) {
            int ko = ks * 32 + quad * 8;
            u16x8 b0 = *(const u16x8*)(m1 + r16 * BB + ko);
            u16x8 b1 = *(const u16x8*)(m1 + (16 + r16) * BB + ko);
            u16x8 a0 = *(const u16x8*)(w2t + (size_t)(F + r16) * H + ko);
            u16x8 a1 = *(const u16x8*)(w2t + (size_t)(F + 16 + r16) * H + ko);
            acc[0][0] = mfma16(a0, b0, acc[0][0]);
            acc[0][1] = mfma16(a0, b1, acc[0][1]);
            acc[1][0] = mfma16(a1, b0, acc[1][0]);
            acc[1][1] = mfma16(a1, b1, acc[1][1]);
        }
        float ep[2] = {0.f, 0.f};
        #pragma unroll
        for (int rt = 0; rt < 2; rt++) {
            int f0 = F + rt * 16 + quad * 4;
            float4 bv = *(const float4*)(be2 + f0);
            float4 wf = *(const float4*)(winf_s + f0);
            #pragma unroll
            for (int ci = 0; ci < 2; ci++) {
                int e = ci * 16 + r16;
                float s0 = silu_f(acc[rt][ci][0] + bv.x);
                float s1 = silu_f(acc[rt][ci][1] + bv.y);
                float s2 = silu_f(acc[rt][ci][2] + bv.z);
                float s3 = silu_f(acc[rt][ci][3] + bv.w);
                sil[rt][ci][0] = s0; sil[rt][ci][1] = s1;
                sil[rt][ci][2] = s2; sil[rt][ci][3] = s3;
                ep[ci] += s0 * wf.x + s1 * wf.y + s2 * wf.z + s3 * wf.w;
                uint2 p = { pkbf(s0, s1), pkbf(s2, s3) };
                *(uint2*)(m2 + e * BB + f0) = p;
            }
        }
        #pragma unroll
        for (int ci = 0; ci < 2; ci++) {
            ep[ci] += __shfl_xor(ep[ci], 16, 64);
            ep[ci] += __shfl_xor(ep[ci], 32, 64);
        }
        if (quad == 0) {
            epart[wv][r16] = ep[0];
            epart[wv][16 + r16] = ep[1];
        }
    }
    __syncthreads();                                               // E

    // eij = sigmoid(sum + binf); 32 threads.
    if (t < EPB) {
        float s = epart[0][t] + epart[1][t] + epart[2][t] + epart[3][t] + binf[0];
        eij_s[t] = 1.0f / (1.0f + __expf(-s));
    }

    // Coord layer: silu(mij @ Wx1) -> dot Wx2 (never materialized).
    {
        f32x4 acc[2][2] = {};
        #pragma unroll
        for (int ks = 0; ks < H / 32; ks++) {
            int ko = ks * 32 + quad * 8;
            u16x8 b0 = *(const u16x8*)(m2 + r16 * BB + ko);
            u16x8 b1 = *(const u16x8*)(m2 + (16 + r16) * BB + ko);
            u16x8 a0 = *(const u16x8*)(wx1t + (size_t)(F + r16) * H + ko);
            u16x8 a1 = *(const u16x8*)(wx1t + (size_t)(F + 16 + r16) * H + ko);
            acc[0][0] = mfma16(a0, b0, acc[0][0]);
            acc[0][1] = mfma16(a0, b1, acc[0][1]);
            acc[1][0] = mfma16(a1, b0, acc[1][0]);
            acc[1][1] = mfma16(a1, b1, acc[1][1]);
        }
        float xp[2] = {0.f, 0.f};
        #pragma unroll
        for (int rt = 0; rt < 2; rt++) {
            int f0 = F + rt * 16 + quad * 4;
            float4 bv = *(const float4*)(bx1 + f0);
            float4 wf = *(const float4*)(wx2_s + f0);
            #pragma unroll
            for (int ci = 0; ci < 2; ci++) {
                xp[ci] += silu_f(acc[rt][ci][0] + bv.x) * wf.x
                        + silu_f(acc[rt][ci][1] + bv.y) * wf.y
                        + silu_f(acc[rt][ci][2] + bv.z) * wf.z
                        + silu_f(acc[rt][ci][3] + bv.w) * wf.w;
            }
        }
        #pragma unroll
        for (int ci = 0; ci < 2; ci++) {
            xp[ci] += __shfl_xor(xp[ci], 16, 64);
            xp[ci] += __shfl_xor(xp[ci], 32, 64);
        }
        if (quad == 0) {
            xpart[wv][r16] = xp[0];
            xpart[wv][16 + r16] = xp[1];
        }
    }
    __syncthreads();                                               // F

    // mi atomics straight from registers: val = sil * eij[e].
    #pragma unroll
    for (int ci = 0; ci < 2; ci++) {
        int e = ci * 16 + r16;
        float eij = eij_s[e];
        float* row = mi + (size_t)dst_s[e] * H;
        #pragma unroll
        for (int rt = 0; rt < 2; rt++) {
            int f0 = F + rt * 16 + quad * 4;
            atomicAdd(row + f0 + 0, sil[rt][ci][0] * eij);
            atomicAdd(row + f0 + 1, sil[rt][ci][1] * eij);
            atomicAdd(row + f0 + 2, sil[rt][ci][2] * eij);
            atomicAdd(row + f0 + 3, sil[rt][ci][3] * eij);
        }
    }

    // dx atomics: 3 threads/edge, each redundantly folds xpart + tanh.
    if (t < EPB * 3) {
        int e = t / 3, dim = t % 3;
        float xs = xpart[0][e] + xpart[1][e] + xpart[2][e] + xpart[3][e];
        float xg = tanhf(xs);
        atomicAdd(&dx[(size_t)dst_s[e] * 3 + dim], relx_s[e][dim] * xg);
    }
}

// ---------------- node kernel (bf16 MFMA) -----------------------------------
__global__ __launch_bounds__(256, 6) void node_kernel(
    const float* __restrict__ h, const float* __restrict__ x,
    const float* __restrict__ mask,
    const unsigned short* __restrict__ wn1t, const float* __restrict__ bn1,
    const unsigned short* __restrict__ wn2t, const float* __restrict__ bn2,
    float* __restrict__ mi_hout, float* __restrict__ dx_xout)
{
    __shared__ unsigned short nzs[NPB * NZB];
    __shared__ unsigned short nbuf[NPB * BB];

    const int t = threadIdx.x;
    const int n0 = blockIdx.x * NPB;

    {
        int r = t >> 3, l = t & 7;
        int n = n0 + r;
        unsigned short* zr = nzs + r * NZB;
        if (n < NN) {
            const float4* mi4 = (const float4*)(mi_hout + (size_t)n * H);
            const float4* h4  = (const float4*)(h + (size_t)n * H);
            float4 v0 = mi4[l * 4 + 0], v1 = mi4[l * 4 + 1];
            float4 v2 = mi4[l * 4 + 2], v3 = mi4[l * 4 + 3];
            uint4 p0 = { pkbf(v0.x, v0.y), pkbf(v0.z, v0.w), pkbf(v1.x, v1.y), pkbf(v1.z, v1.w) };
            uint4 p1 = { pkbf(v2.x, v2.y), pkbf(v2.z, v2.w), pkbf(v3.x, v3.y), pkbf(v3.z, v3.w) };
            *(uint4*)(zr + l * 16) = p0;
            *(uint4*)(zr + l * 16 + 8) = p1;
            float4 w0 = h4[l * 4 + 0], w1 = h4[l * 4 + 1];
            float4 w2 = h4[l * 4 + 2], w3 = h4[l * 4 + 3];
            uint4 q0 = { pkbf(w0.x, w0.y), pkbf(w0.z, w0.w), pkbf(w1.x, w1.y), pkbf(w1.z, w1.w) };
            uint4 q1 = { pkbf(w2.x, w2.y), pkbf(w2.z, w2.w), pkbf(w3.x, w3.y), pkbf(w3.z, w3.w) };
            *(uint4*)(zr + 128 + l * 16) = q0;
            *(uint4*)(zr + 128 + l * 16 + 8) = q1;
        } else {
            uint4 zf = {0u, 0u, 0u, 0u};
            *(uint4*)(zr + l * 16) = zf;
            *(uint4*)(zr + l * 16 + 8) = zf;
            *(uint4*)(zr + 128 + l * 16) = zf;
            *(uint4*)(zr + 128 + l * 16 + 8) = zf;
        }
    }

    float xo = 0.f;
    int xn = -1, xdim = 0;
    if (t < NPB * 3) {
        int r = t / 3; xdim = t % 3;
        int n = n0 + r;
        if (n < NN) {
            xn = n;
            xo = x[(size_t)n * 3 + xdim] + dx_xout[(size_t)n * 3 + xdim] * mask[n];
        }
    }
    __syncthreads();

    if (xn >= 0) dx_xout[(size_t)xn * 3 + xdim] = xo;

    const int wv = t >> 6, lane = t & 63;
    const int quad = lane >> 4, r16 = lane & 15;

    layer_mfma<2 * H, NZB, false>(nzs, wn1t, bn1, nbuf, wv, quad, r16);
    __syncthreads();

    {
        f32x4 acc[2][2] = {};
        const int F = wv * 32;
        #pragma unroll
        for (int ks = 0; ks < H / 32; ks++) {
            int ko = ks * 32 + quad * 8;
            u16x8 b0 = *(const u16x8*)(nbuf + r16 * BB + ko);
            u16x8 b1 = *(const u16x8*)(nbuf + (16 + r16) * BB + ko);
            u16x8 a0 = *(const u16x8*)(wn2t + (size_t)(F + r16) * H + ko);
            u16x8 a1 = *(const u16x8*)(wn2t + (size_t)(F + 16 + r16) * H + ko);
            acc[0][0] = mfma16(a0, b0, acc[0][0]);
            acc[0][1] = mfma16(a0, b1, acc[0][1]);
            acc[1][0] = mfma16(a1, b0, acc[1][0]);
            acc[1][1] = mfma16(a1, b1, acc[1][1]);
        }
        #pragma unroll
        for (int rt = 0; rt < 2; rt++) {
            int f0 = F + rt * 16 + quad * 4;
            float4 bv = *(const float4*)(bn2 + f0);
            #pragma unroll
            for (int ci = 0; ci < 2; ci++) {
                int n = n0 + ci * 16 + r16;
                if (n < NN) {
                    float4 hv = *(const float4*)(h + (size_t)n * H + f0);
                    float4 o;
                    o.x = hv.x + acc[rt][ci][0] + bv.x;
                    o.y = hv.y + acc[rt][ci][1] + bv.y;
                    o.z = hv.z + acc[rt][ci][2] + bv.z;
                    o.w = hv.w + acc[rt][ci][3] + bv.w;
                    *(float4*)(mi_hout + (size_t)n * H + f0) = o;
                }
            }
        }
    }
}

extern "C" void kernel_launch(void* const* d_in, const int* in_sizes, int n_in,
                              void* d_out, int out_size, void* d_ws, size_t ws_size,
                              hipStream_t stream) {
    const float* h     = (const float*)d_in[0];
    const float* x     = (const float*)d_in[1];
    const int*   ei    = (const int*)d_in[2];
    const float* mask  = (const float*)d_in[3];
    const float* eattr = (const float*)d_in[4];
    const float* We1   = (const float*)d_in[5];
    const float* be1   = (const float*)d_in[6];
    const float* We2   = (const float*)d_in[7];
    const float* be2   = (const float*)d_in[8];
    const float* Winf  = (const float*)d_in[9];
    const float* binf  = (const float*)d_in[10];
    const float* Wx1   = (const float*)d_in[11];
    const float* bx1   = (const float*)d_in[12];
    const float* Wx2   = (const float*)d_in[13];
    const float* Wn1   = (const float*)d_in[14];
    const float* bn1   = (const float*)d_in[15];
    const float* Wn2   = (const float*)d_in[16];
    const float* bn2   = (const float*)d_in[17];

    float* mi = (float*)d_out;
    float* dx = mi + (size_t)NN * H;

    unsigned short* w1t  = (unsigned short*)d_ws;
    unsigned short* w2t  = w1t + 128 * KP1;
    unsigned short* wx1t = w2t + 128 * H;
    unsigned short* wn1t = wx1t + 128 * H;
    unsigned short* wn2t = wn1t + 128 * 256;

    const int wconv_total = 128 * KP1 + 3 * 128 * H + 128 * 256;
    convert_weights<<<(wconv_total + 255) / 256, 256, 0, stream>>>(
        We1, We2, Wx1, Wn1, Wn2, w1t, w2t, wx1t, wn1t, wn2t);

    const int total4 = (NN * H + NN * 3) / 4;
    zero_kernel<<<(total4 + 255) / 256, 256, 0, stream>>>((float4*)d_out, total4);

    edge_kernel<<<NE / EPB, 256, 0, stream>>>(
        h, x, ei, eattr, w1t, be1, w2t, be2, Winf, binf, wx1t, bx1, Wx2, mi, dx);

    node_kernel<<<(NN + NPB - 1) / NPB, 256, 0, stream>>>(
        h, x, mask, wn1t, bn1, wn2t, bn2, mi, dx);
}

// Round 6
// 524.963 us; speedup vs baseline: 2.4450x; 2.4450x over previous
//
#include <hip/hip_runtime.h>
#include <math.h>

#define NN 50000
#define NE 640000
#define H 128
#define EPB 32        // edges per block
#define NPB 32        // nodes per block
#define ZB 296        // LDS stride (bf16) for z rows (592 B)
#define BB 136        // LDS stride (bf16) for 128-wide buffers (272 B)
#define KP1 288       // padded K for layer 1 (280 -> 288)
#define NZB 264       // LDS stride (bf16) for node 256-wide input (528 B)

typedef __attribute__((ext_vector_type(8))) unsigned short u16x8;
typedef __attribute__((ext_vector_type(8))) __bf16 bf16x8;
typedef __attribute__((ext_vector_type(2))) __bf16 bf16x2;
typedef __attribute__((ext_vector_type(4))) float f32x4;

__device__ __forceinline__ float silu_f(float v) {
    return v / (1.0f + __expf(-v));
}

__device__ __forceinline__ unsigned short f2bf(float f) {
    unsigned int u = __builtin_bit_cast(unsigned int, f);
    u += 0x7FFFu + ((u >> 16) & 1u);   // RNE
    return (unsigned short)(u >> 16);
}

__device__ __forceinline__ float bf2f(unsigned short s) {
    unsigned int u = ((unsigned int)s) << 16;
    return __builtin_bit_cast(float, u);
}

__device__ __forceinline__ unsigned int pkbf(float lo, float hi) {
#if __has_builtin(__builtin_amdgcn_cvt_pk_bf16_f32)
    bf16x2 v = __builtin_amdgcn_cvt_pk_bf16_f32(lo, hi);
    unsigned int r; __builtin_memcpy(&r, &v, 4); return r;
#else
    return (unsigned int)f2bf(lo) | ((unsigned int)f2bf(hi) << 16);
#endif
}

__device__ __forceinline__ f32x4 mfma16(u16x8 a, u16x8 b, f32x4 c) {
    return __builtin_amdgcn_mfma_f32_16x16x32_bf16(
        __builtin_bit_cast(bf16x8, a), __builtin_bit_cast(bf16x8, b), c, 0, 0, 0);
}

// Transposed-role GEMM: D = W^T (A) x in^T (B); lane holds features
// F+rt*16+quad*4..+3 for edges ci*16+r16. Epilogue silu -> bf16 LDS write.
template<int KT, int INSTR, bool SYNC_BEFORE_EPI>
__device__ __forceinline__ void layer_mfma(
    const unsigned short* __restrict__ inbuf,
    const unsigned short* __restrict__ wt,
    const float* __restrict__ bias,
    unsigned short* __restrict__ outbuf,
    int wv, int quad, int r16)
{
    f32x4 acc[2][2] = {};
    const int F = wv * 32;
    #pragma unroll
    for (int ks = 0; ks < KT / 32; ks++) {
        int ko = ks * 32 + quad * 8;
        u16x8 b0 = *(const u16x8*)(inbuf + r16 * INSTR + ko);
        u16x8 b1 = *(const u16x8*)(inbuf + (16 + r16) * INSTR + ko);
        u16x8 a0 = *(const u16x8*)(wt + (size_t)(F + r16) * KT + ko);
        u16x8 a1 = *(const u16x8*)(wt + (size_t)(F + 16 + r16) * KT + ko);
        acc[0][0] = mfma16(a0, b0, acc[0][0]);
        acc[0][1] = mfma16(a0, b1, acc[0][1]);
        acc[1][0] = mfma16(a1, b0, acc[1][0]);
        acc[1][1] = mfma16(a1, b1, acc[1][1]);
    }
    if (SYNC_BEFORE_EPI) __syncthreads();
    #pragma unroll
    for (int rt = 0; rt < 2; rt++) {
        int f0 = F + rt * 16 + quad * 4;
        float4 bv = *(const float4*)(bias + f0);
        #pragma unroll
        for (int ci = 0; ci < 2; ci++) {
            int e = ci * 16 + r16;
            float s0 = silu_f(acc[rt][ci][0] + bv.x);
            float s1 = silu_f(acc[rt][ci][1] + bv.y);
            float s2 = silu_f(acc[rt][ci][2] + bv.z);
            float s3 = silu_f(acc[rt][ci][3] + bv.w);
            uint2 p = { pkbf(s0, s1), pkbf(s2, s3) };
            *(uint2*)(outbuf + e * BB + f0) = p;
        }
    }
}

// ---------------- weight conversion: fp32 [k][n] -> bf16 [n][k] -------------
__global__ __launch_bounds__(256) void convert_weights(
    const float* __restrict__ We1, const float* __restrict__ We2,
    const float* __restrict__ Wx1, const float* __restrict__ Wn1,
    const float* __restrict__ Wn2,
    unsigned short* __restrict__ w1t, unsigned short* __restrict__ w2t,
    unsigned short* __restrict__ wx1t, unsigned short* __restrict__ wn1t,
    unsigned short* __restrict__ wn2t)
{
    int i = blockIdx.x * 256 + threadIdx.x;
    const int S1 = 128 * KP1;
    const int S2 = 128 * 128;
    const int S3 = 128 * 256;
    if (i < S1) {
        int n = i / KP1, k = i % KP1;
        w1t[i] = (k < 280) ? f2bf(We1[k * H + n]) : (unsigned short)0;
    } else if (i < S1 + S2) {
        int j = i - S1; int n = j / H, k = j % H;
        w2t[j] = f2bf(We2[k * H + n]);
    } else if (i < S1 + 2 * S2) {
        int j = i - S1 - S2; int n = j / H, k = j % H;
        wx1t[j] = f2bf(Wx1[k * H + n]);
    } else if (i < S1 + 2 * S2 + S3) {
        int j = i - S1 - 2 * S2; int n = j / 256, k = j % 256;
        wn1t[j] = f2bf(Wn1[k * H + n]);
    } else if (i < S1 + 3 * S2 + S3) {
        int j = i - S1 - 2 * S2 - S3; int n = j / H, k = j % H;
        wn2t[j] = f2bf(Wn2[k * H + n]);
    }
}

__global__ __launch_bounds__(256) void zero_kernel(float4* __restrict__ p, int n4) {
    int i = blockIdx.x * 256 + threadIdx.x;
    if (i < n4) p[i] = make_float4(0.f, 0.f, 0.f, 0.f);
}

// ---------------- edge kernel -----------------------------------------------
__global__ __launch_bounds__(256, 5) void edge_kernel(
    const float* __restrict__ h, const float* __restrict__ x,
    const int* __restrict__ ei, const float* __restrict__ edge_attr,
    const unsigned short* __restrict__ w1t, const float* __restrict__ be1,
    const unsigned short* __restrict__ w2t, const float* __restrict__ be2,
    const float* __restrict__ Winf, const float* __restrict__ binf,
    const unsigned short* __restrict__ wx1t, const float* __restrict__ bx1,
    const float* __restrict__ Wx2,
    float* __restrict__ mi, float* __restrict__ dx)
{
    __shared__ unsigned short zs[EPB * ZB];   // z input; aliased as m1 after L1
    __shared__ unsigned short m2[EPB * BB];   // mij (bf16)
    __shared__ float relx_s[EPB][3];
    __shared__ float eij_s[EPB];
    __shared__ float epart[4][EPB];
    __shared__ float xpart[4][EPB];
    __shared__ int dst_s[EPB];
    __shared__ int src_s[EPB];
    __shared__ float winf_s[H];
    __shared__ float wx2_s[H];

    unsigned short* m1 = zs;   // alias: zs dead after layer-1 K-loop (+barrier)

    const int t = threadIdx.x;
    const int e0 = blockIdx.x * EPB;

    if (t < EPB) {
        src_s[t] = ei[e0 + t];
        dst_s[t] = ei[NE + e0 + t];
    }
    if (t >= 128 && t < 256) {
        winf_s[t - 128] = Winf[t - 128];
        wx2_s[t - 128] = Wx2[t - 128];
    }
    __syncthreads();                                               // A

    // Gather h[dst] -> z[0:128], h[src] -> z[128:256]; 8 lanes/edge.
    {
        int e = t >> 3, l = t & 7;
        int s = src_s[e], d = dst_s[e];
        const float4* hd = (const float4*)(h + (size_t)d * H);
        const float4* hs = (const float4*)(h + (size_t)s * H);
        unsigned short* zr = zs + e * ZB;
        float4 v0 = hd[l * 4 + 0], v1 = hd[l * 4 + 1];
        float4 v2 = hd[l * 4 + 2], v3 = hd[l * 4 + 3];
        uint4 p0 = { pkbf(v0.x, v0.y), pkbf(v0.z, v0.w), pkbf(v1.x, v1.y), pkbf(v1.z, v1.w) };
        uint4 p1 = { pkbf(v2.x, v2.y), pkbf(v2.z, v2.w), pkbf(v3.x, v3.y), pkbf(v3.z, v3.w) };
        *(uint4*)(zr + l * 16) = p0;
        *(uint4*)(zr + l * 16 + 8) = p1;
        float4 w0 = hs[l * 4 + 0], w1 = hs[l * 4 + 1];
        float4 w2 = hs[l * 4 + 2], w3 = hs[l * 4 + 3];
        uint4 q0 = { pkbf(w0.x, w0.y), pkbf(w0.z, w0.w), pkbf(w1.x, w1.y), pkbf(w1.z, w1.w) };
        uint4 q1 = { pkbf(w2.x, w2.y), pkbf(w2.z, w2.w), pkbf(w3.x, w3.y), pkbf(w3.z, w3.w) };
        *(uint4*)(zr + 128 + l * 16) = q0;
        *(uint4*)(zr + 128 + l * 16 + 8) = q1;
    }
    // Geometry + gaussians + edge_attr + pad; 1 thread/edge.
    if (t < EPB) {
        int s = src_s[t], d = dst_s[t];
        float rx = x[d * 3 + 0] - x[s * 3 + 0];
        float ry = x[d * 3 + 1] - x[s * 3 + 1];
        float rz = x[d * 3 + 2] - x[s * 3 + 2];
        float d2 = rx * rx + ry * ry + rz * rz;
        float dd = sqrtf(d2 + 1e-8f);
        float inv = 1.0f / (dd + 1.0f);
        relx_s[t][0] = rx * inv;
        relx_s[t][1] = ry * inv;
        relx_s[t][2] = rz * inv;
        const float step = 10.0f / 19.0f;
        const float coeff = -0.5f / (step * step);
        unsigned short* zr = zs + t * ZB;
        #pragma unroll
        for (int g = 0; g < 20; g++) {
            float df = dd - step * (float)g;
            zr[256 + g] = f2bf(__expf(coeff * df * df));
        }
        #pragma unroll
        for (int j = 0; j < 4; j++)
            zr[276 + j] = f2bf(edge_attr[(size_t)(e0 + t) * 4 + j]);
        #pragma unroll
        for (int j = 280; j < ZB; j++) zr[j] = 0;
    }
    __syncthreads();                                               // B

    const int wv = t >> 6, lane = t & 63;
    const int quad = lane >> 4, r16 = lane & 15;
    const int F = wv * 32;

    // Layer 1: (z @ We1)^T -> silu -> m1 (aliases zs; barrier C inside)
    layer_mfma<KP1, ZB, true>(zs, w1t, be1, m1, wv, quad, r16);
    __syncthreads();                                               // D

    // Layer 2: mij -> m2 (bf16). eij partial dot fused from accumulators.
    {
        f32x4 acc[2][2] = {};
        #pragma unroll
        for (int ks = 0; ks < H / 32; ks++) {
            int ko = ks * 32 + quad * 8;
            u16x8 b0 = *(const u16x8*)(m1 + r16 * BB + ko);
            u16x8 b1 = *(const u16x8*)(m1 + (16 + r16) * BB + ko);
            u16x8 a0 = *(const u16x8*)(w2t + (size_t)(F + r16) * H + ko);
            u16x8 a1 = *(const u16x8*)(w2t + (size_t)(F + 16 + r16) * H + ko);
            acc[0][0] = mfma16(a0, b0, acc[0][0]);
            acc[0][1] = mfma16(a0, b1, acc[0][1]);
            acc[1][0] = mfma16(a1, b0, acc[1][0]);
            acc[1][1] = mfma16(a1, b1, acc[1][1]);
        }
        float ep[2] = {0.f, 0.f};
        #pragma unroll
        for (int rt = 0; rt < 2; rt++) {
            int f0 = F + rt * 16 + quad * 4;
            float4 bv = *(const float4*)(be2 + f0);
            float4 wf = *(const float4*)(winf_s + f0);
            #pragma unroll
            for (int ci = 0; ci < 2; ci++) {
                int e = ci * 16 + r16;
                float s0 = silu_f(acc[rt][ci][0] + bv.x);
                float s1 = silu_f(acc[rt][ci][1] + bv.y);
                float s2 = silu_f(acc[rt][ci][2] + bv.z);
                float s3 = silu_f(acc[rt][ci][3] + bv.w);
                ep[ci] += s0 * wf.x + s1 * wf.y + s2 * wf.z + s3 * wf.w;
                uint2 p = { pkbf(s0, s1), pkbf(s2, s3) };
                *(uint2*)(m2 + e * BB + f0) = p;
            }
        }
        #pragma unroll
        for (int ci = 0; ci < 2; ci++) {
            ep[ci] += __shfl_xor(ep[ci], 16, 64);
            ep[ci] += __shfl_xor(ep[ci], 32, 64);
        }
        if (quad == 0) {
            epart[wv][r16] = ep[0];
            epart[wv][16 + r16] = ep[1];
        }
    }
    __syncthreads();                                               // E

    // eij = sigmoid(sum + binf); 32 threads.
    if (t < EPB) {
        float s = epart[0][t] + epart[1][t] + epart[2][t] + epart[3][t] + binf[0];
        eij_s[t] = 1.0f / (1.0f + __expf(-s));
    }

    // Coord layer: silu(mij @ Wx1) . Wx2, never materialized.
    {
        f32x4 acc[2][2] = {};
        #pragma unroll
        for (int ks = 0; ks < H / 32; ks++) {
            int ko = ks * 32 + quad * 8;
            u16x8 b0 = *(const u16x8*)(m2 + r16 * BB + ko);
            u16x8 b1 = *(const u16x8*)(m2 + (16 + r16) * BB + ko);
            u16x8 a0 = *(const u16x8*)(wx1t + (size_t)(F + r16) * H + ko);
            u16x8 a1 = *(const u16x8*)(wx1t + (size_t)(F + 16 + r16) * H + ko);
            acc[0][0] = mfma16(a0, b0, acc[0][0]);
            acc[0][1] = mfma16(a0, b1, acc[0][1]);
            acc[1][0] = mfma16(a1, b0, acc[1][0]);
            acc[1][1] = mfma16(a1, b1, acc[1][1]);
        }
        float xp[2] = {0.f, 0.f};
        #pragma unroll
        for (int rt = 0; rt < 2; rt++) {
            int f0 = F + rt * 16 + quad * 4;
            float4 bv = *(const float4*)(bx1 + f0);
            float4 wf = *(const float4*)(wx2_s + f0);
            #pragma unroll
            for (int ci = 0; ci < 2; ci++) {
                xp[ci] += silu_f(acc[rt][ci][0] + bv.x) * wf.x
                        + silu_f(acc[rt][ci][1] + bv.y) * wf.y
                        + silu_f(acc[rt][ci][2] + bv.z) * wf.z
                        + silu_f(acc[rt][ci][3] + bv.w) * wf.w;
            }
        }
        #pragma unroll
        for (int ci = 0; ci < 2; ci++) {
            xp[ci] += __shfl_xor(xp[ci], 16, 64);
            xp[ci] += __shfl_xor(xp[ci], 32, 64);
        }
        if (quad == 0) {
            xpart[wv][r16] = xp[0];
            xpart[wv][16 + r16] = xp[1];
        }
    }
    __syncthreads();                                               // F

    // Segment sums: contiguous per-edge atomics (R4-proven pattern).
    {
        int k = t & 127, eh = t >> 7;
        for (int e = eh; e < EPB; e += 2) {
            float mv = bf2f(m2[e * BB + k]) * eij_s[e];
            atomicAdd(&mi[(size_t)dst_s[e] * H + k], mv);
        }
        if (t < EPB * 3) {
            int e = t / 3, dim = t % 3;
            float xs = xpart[0][e] + xpart[1][e] + xpart[2][e] + xpart[3][e];
            float xg = tanhf(xs);
            atomicAdd(&dx[(size_t)dst_s[e] * 3 + dim], relx_s[e][dim] * xg);
        }
    }
}

// ---------------- node kernel (bf16 MFMA) -----------------------------------
__global__ __launch_bounds__(256, 6) void node_kernel(
    const float* __restrict__ h, const float* __restrict__ x,
    const float* __restrict__ mask,
    const unsigned short* __restrict__ wn1t, const float* __restrict__ bn1,
    const unsigned short* __restrict__ wn2t, const float* __restrict__ bn2,
    float* __restrict__ mi_hout, float* __restrict__ dx_xout)
{
    __shared__ unsigned short nzs[NPB * NZB];
    __shared__ unsigned short nbuf[NPB * BB];

    const int t = threadIdx.x;
    const int n0 = blockIdx.x * NPB;

    {
        int r = t >> 3, l = t & 7;
        int n = n0 + r;
        unsigned short* zr = nzs + r * NZB;
        if (n < NN) {
            const float4* mi4 = (const float4*)(mi_hout + (size_t)n * H);
            const float4* h4  = (const float4*)(h + (size_t)n * H);
            float4 v0 = mi4[l * 4 + 0], v1 = mi4[l * 4 + 1];
            float4 v2 = mi4[l * 4 + 2], v3 = mi4[l * 4 + 3];
            uint4 p0 = { pkbf(v0.x, v0.y), pkbf(v0.z, v0.w), pkbf(v1.x, v1.y), pkbf(v1.z, v1.w) };
            uint4 p1 = { pkbf(v2.x, v2.y), pkbf(v2.z, v2.w), pkbf(v3.x, v3.y), pkbf(v3.z, v3.w) };
            *(uint4*)(zr + l * 16) = p0;
            *(uint4*)(zr + l * 16 + 8) = p1;
            float4 w0 = h4[l * 4 + 0], w1 = h4[l * 4 + 1];
            float4 w2 = h4[l * 4 + 2], w3 = h4[l * 4 + 3];
            uint4 q0 = { pkbf(w0.x, w0.y), pkbf(w0.z, w0.w), pkbf(w1.x, w1.y), pkbf(w1.z, w1.w) };
            uint4 q1 = { pkbf(w2.x, w2.y), pkbf(w2.z, w2.w), pkbf(w3.x, w3.y), pkbf(w3.z, w3.w) };
            *(uint4*)(zr + 128 + l * 16) = q0;
            *(uint4*)(zr + 128 + l * 16 + 8) = q1;
        } else {
            uint4 zf = {0u, 0u, 0u, 0u};
            *(uint4*)(zr + l * 16) = zf;
            *(uint4*)(zr + l * 16 + 8) = zf;
            *(uint4*)(zr + 128 + l * 16) = zf;
            *(uint4*)(zr + 128 + l * 16 + 8) = zf;
        }
    }

    float xo = 0.f;
    int xn = -1, xdim = 0;
    if (t < NPB * 3) {
        int r = t / 3; xdim = t % 3;
        int n = n0 + r;
        if (n < NN) {
            xn = n;
            xo = x[(size_t)n * 3 + xdim] + dx_xout[(size_t)n * 3 + xdim] * mask[n];
        }
    }
    __syncthreads();

    if (xn >= 0) dx_xout[(size_t)xn * 3 + xdim] = xo;

    const int wv = t >> 6, lane = t & 63;
    const int quad = lane >> 4, r16 = lane & 15;

    layer_mfma<2 * H, NZB, false>(nzs, wn1t, bn1, nbuf, wv, quad, r16);
    __syncthreads();

    {
        f32x4 acc[2][2] = {};
        const int F = wv * 32;
        #pragma unroll
        for (int ks = 0; ks < H / 32; ks++) {
            int ko = ks * 32 + quad * 8;
            u16x8 b0 = *(const u16x8*)(nbuf + r16 * BB + ko);
            u16x8 b1 = *(const u16x8*)(nbuf + (16 + r16) * BB + ko);
            u16x8 a0 = *(const u16x8*)(wn2t + (size_t)(F + r16) * H + ko);
            u16x8 a1 = *(const u16x8*)(wn2t + (size_t)(F + 16 + r16) * H + ko);
            acc[0][0] = mfma16(a0, b0, acc[0][0]);
            acc[0][1] = mfma16(a0, b1, acc[0][1]);
            acc[1][0] = mfma16(a1, b0, acc[1][0]);
            acc[1][1] = mfma16(a1, b1, acc[1][1]);
        }
        #pragma unroll
        for (int rt = 0; rt < 2; rt++) {
            int f0 = F + rt * 16 + quad * 4;
            float4 bv = *(const float4*)(bn2 + f0);
            #pragma unroll
            for (int ci = 0; ci < 2; ci++) {
                int n = n0 + ci * 16 + r16;
                if (n < NN) {
                    float4 hv = *(const float4*)(h + (size_t)n * H + f0);
                    float4 o;
                    o.x = hv.x + acc[rt][ci][0] + bv.x;
                    o.y = hv.y + acc[rt][ci][1] + bv.y;
                    o.z = hv.z + acc[rt][ci][2] + bv.z;
                    o.w = hv.w + acc[rt][ci][3] + bv.w;
                    *(float4*)(mi_hout + (size_t)n * H + f0) = o;
                }
            }
        }
    }
}

extern "C" void kernel_launch(void* const* d_in, const int* in_sizes, int n_in,
                              void* d_out, int out_size, void* d_ws, size_t ws_size,
                              hipStream_t stream) {
    const float* h     = (const float*)d_in[0];
    const float* x     = (const float*)d_in[1];
    const int*   ei    = (const int*)d_in[2];
    const float* mask  = (const float*)d_in[3];
    const float* eattr = (const float*)d_in[4];
    const float* We1   = (const float*)d_in[5];
    const float* be1   = (const float*)d_in[6];
    const float* We2   = (const float*)d_in[7];
    const float* be2   = (const float*)d_in[8];
    const float* Winf  = (const float*)d_in[9];
    const float* binf  = (const float*)d_in[10];
    const float* Wx1   = (const float*)d_in[11];
    const float* bx1   = (const float*)d_in[12];
    const float* Wx2   = (const float*)d_in[13];
    const float* Wn1   = (const float*)d_in[14];
    const float* bn1   = (const float*)d_in[15];
    const float* Wn2   = (const float*)d_in[16];
    const float* bn2   = (const float*)d_in[17];

    float* mi = (float*)d_out;
    float* dx = mi + (size_t)NN * H;

    unsigned short* w1t  = (unsigned short*)d_ws;
    unsigned short* w2t  = w1t + 128 * KP1;
    unsigned short* wx1t = w2t + 128 * H;
    unsigned short* wn1t = wx1t + 128 * H;
    unsigned short* wn2t = wn1t + 128 * 256;

    const int wconv_total = 128 * KP1 + 3 * 128 * H + 128 * 256;
    convert_weights<<<(wconv_total + 255) / 256, 256, 0, stream>>>(
        We1, We2, Wx1, Wn1, Wn2, w1t, w2t, wx1t, wn1t, wn2t);

    const int total4 = (NN * H + NN * 3) / 4;
    zero_kernel<<<(total4 + 255) / 256, 256, 0, stream>>>((float4*)d_out, total4);

    edge_kernel<<<NE / EPB, 256, 0, stream>>>(
        h, x, ei, eattr, w1t, be1, w2t, be2, Winf, binf, wx1t, bx1, Wx2, mi, dx);

    node_kernel<<<(NN + NPB - 1) / NPB, 256, 0, stream>>>(
        h, x, mask, wn1t, bn1, wn2t, bn2, mi, dx);
}

// Round 7
// 522.208 us; speedup vs baseline: 2.4579x; 1.0053x over previous
//
#include <hip/hip_runtime.h>
#include <math.h>

#define NN 50000
#define NE 640000
#define H 128
#define EPB 32        // edges per block
#define NPB 32        // nodes per block
#define ZB 296        // LDS stride (bf16) for z rows (592 B)
#define BB 136        // LDS stride (bf16) for 128-wide buffers (272 B)
#define KP1 288       // padded K for layer 1 (280 -> 288)
#define NZB 264       // LDS stride (bf16) for node 256-wide input (528 B)

typedef __attribute__((ext_vector_type(8))) unsigned short u16x8;
typedef __attribute__((ext_vector_type(8))) __bf16 bf16x8;
typedef __attribute__((ext_vector_type(2))) __bf16 bf16x2;
typedef __attribute__((ext_vector_type(4))) float f32x4;

__device__ __forceinline__ float frcp(float x) {
#if __has_builtin(__builtin_amdgcn_rcpf)
    return __builtin_amdgcn_rcpf(x);   // raw v_rcp_f32, no Newton refine
#else
    return 1.0f / x;
#endif
}

__device__ __forceinline__ float silu_f(float v) {
    return v * frcp(1.0f + __expf(-v));
}

__device__ __forceinline__ float sigmoid_f(float v) {
    return frcp(1.0f + __expf(-v));
}

__device__ __forceinline__ float tanh_f(float v) {
    // tanh(x) = 1 - 2/(e^{2x}+1); exact at +-inf, fine for |err|~1e-6
    return 1.0f - 2.0f * frcp(1.0f + __expf(2.0f * v));
}

__device__ __forceinline__ unsigned short f2bf(float f) {
    unsigned int u = __builtin_bit_cast(unsigned int, f);
    u += 0x7FFFu + ((u >> 16) & 1u);   // RNE
    return (unsigned short)(u >> 16);
}

__device__ __forceinline__ float bf2f(unsigned short s) {
    unsigned int u = ((unsigned int)s) << 16;
    return __builtin_bit_cast(float, u);
}

__device__ __forceinline__ unsigned int pkbf(float lo, float hi) {
#if __has_builtin(__builtin_amdgcn_cvt_pk_bf16_f32)
    bf16x2 v = __builtin_amdgcn_cvt_pk_bf16_f32(lo, hi);
    unsigned int r; __builtin_memcpy(&r, &v, 4); return r;
#else
    return (unsigned int)f2bf(lo) | ((unsigned int)f2bf(hi) << 16);
#endif
}

__device__ __forceinline__ f32x4 mfma16(u16x8 a, u16x8 b, f32x4 c) {
    return __builtin_amdgcn_mfma_f32_16x16x32_bf16(
        __builtin_bit_cast(bf16x8, a), __builtin_bit_cast(bf16x8, b), c, 0, 0, 0);
}

// Transposed-role GEMM: D = W^T (A) x in^T (B); lane holds features
// F+rt*16+quad*4..+3 for edges ci*16+r16. Epilogue silu -> bf16 LDS write.
template<int KT, int INSTR, bool SYNC_BEFORE_EPI>
__device__ __forceinline__ void layer_mfma(
    const unsigned short* __restrict__ inbuf,
    const unsigned short* __restrict__ wt,
    const float* __restrict__ bias,
    unsigned short* __restrict__ outbuf,
    int wv, int quad, int r16)
{
    f32x4 acc[2][2] = {};
    const int F = wv * 32;
    #pragma unroll
    for (int ks = 0; ks < KT / 32; ks++) {
        int ko = ks * 32 + quad * 8;
        u16x8 b0 = *(const u16x8*)(inbuf + r16 * INSTR + ko);
        u16x8 b1 = *(const u16x8*)(inbuf + (16 + r16) * INSTR + ko);
        u16x8 a0 = *(const u16x8*)(wt + (size_t)(F + r16) * KT + ko);
        u16x8 a1 = *(const u16x8*)(wt + (size_t)(F + 16 + r16) * KT + ko);
        acc[0][0] = mfma16(a0, b0, acc[0][0]);
        acc[0][1] = mfma16(a0, b1, acc[0][1]);
        acc[1][0] = mfma16(a1, b0, acc[1][0]);
        acc[1][1] = mfma16(a1, b1, acc[1][1]);
    }
    if (SYNC_BEFORE_EPI) __syncthreads();
    #pragma unroll
    for (int rt = 0; rt < 2; rt++) {
        int f0 = F + rt * 16 + quad * 4;
        float4 bv = *(const float4*)(bias + f0);
        #pragma unroll
        for (int ci = 0; ci < 2; ci++) {
            int e = ci * 16 + r16;
            float s0 = silu_f(acc[rt][ci][0] + bv.x);
            float s1 = silu_f(acc[rt][ci][1] + bv.y);
            float s2 = silu_f(acc[rt][ci][2] + bv.z);
            float s3 = silu_f(acc[rt][ci][3] + bv.w);
            uint2 p = { pkbf(s0, s1), pkbf(s2, s3) };
            *(uint2*)(outbuf + e * BB + f0) = p;
        }
    }
}

// ---------------- weight conversion: fp32 [k][n] -> bf16 [n][k] -------------
__global__ __launch_bounds__(256) void convert_weights(
    const float* __restrict__ We1, const float* __restrict__ We2,
    const float* __restrict__ Wx1, const float* __restrict__ Wn1,
    const float* __restrict__ Wn2,
    unsigned short* __restrict__ w1t, unsigned short* __restrict__ w2t,
    unsigned short* __restrict__ wx1t, unsigned short* __restrict__ wn1t,
    unsigned short* __restrict__ wn2t)
{
    int i = blockIdx.x * 256 + threadIdx.x;
    const int S1 = 128 * KP1;
    const int S2 = 128 * 128;
    const int S3 = 128 * 256;
    if (i < S1) {
        int n = i / KP1, k = i % KP1;
        w1t[i] = (k < 280) ? f2bf(We1[k * H + n]) : (unsigned short)0;
    } else if (i < S1 + S2) {
        int j = i - S1; int n = j / H, k = j % H;
        w2t[j] = f2bf(We2[k * H + n]);
    } else if (i < S1 + 2 * S2) {
        int j = i - S1 - S2; int n = j / H, k = j % H;
        wx1t[j] = f2bf(Wx1[k * H + n]);
    } else if (i < S1 + 2 * S2 + S3) {
        int j = i - S1 - 2 * S2; int n = j / 256, k = j % 256;
        wn1t[j] = f2bf(Wn1[k * H + n]);
    } else if (i < S1 + 3 * S2 + S3) {
        int j = i - S1 - 2 * S2 - S3; int n = j / H, k = j % H;
        wn2t[j] = f2bf(Wn2[k * H + n]);
    }
}

__global__ __launch_bounds__(256) void zero_kernel(float4* __restrict__ p, int n4) {
    int i = blockIdx.x * 256 + threadIdx.x;
    if (i < n4) p[i] = make_float4(0.f, 0.f, 0.f, 0.f);
}

// ---------------- edge kernel -----------------------------------------------
// LDS ~21.6 KB -> 7 blocks/CU.
__global__ __launch_bounds__(256, 7) void edge_kernel(
    const float* __restrict__ h, const float* __restrict__ x,
    const int* __restrict__ ei, const float* __restrict__ edge_attr,
    const unsigned short* __restrict__ w1t, const float* __restrict__ be1,
    const unsigned short* __restrict__ w2t, const float* __restrict__ be2,
    const float* __restrict__ Winf, const float* __restrict__ binf,
    const unsigned short* __restrict__ wx1t, const float* __restrict__ bx1,
    const float* __restrict__ Wx2,
    float* __restrict__ mi, float* __restrict__ dx)
{
    // zs dead after L1 K-loop: m1 aliases zs[0:EPB*BB], m2 aliases the next
    // EPB*BB shorts (both fit: 2*EPB*BB = 8704 <= EPB*ZB = 9472).
    __shared__ unsigned short zs[EPB * ZB];
    __shared__ float relx_s[EPB][3];
    __shared__ float eij_s[EPB];
    __shared__ float epart[4][EPB];
    __shared__ float xpart[4][EPB];
    __shared__ int dst_s[EPB];
    __shared__ float winf_s[H];
    __shared__ float wx2_s[H];

    unsigned short* m1 = zs;
    unsigned short* m2 = zs + EPB * BB;

    const int t = threadIdx.x;
    const int e0 = blockIdx.x * EPB;

    if (t >= 128 && t < 256) {
        winf_s[t - 128] = Winf[t - 128];
        wx2_s[t - 128] = Wx2[t - 128];
    }

    // Gather h[dst] -> z[0:128], h[src] -> z[128:256]; 8 lanes/edge.
    // Indices read straight from ei (L1 broadcast) - no staging barrier.
    {
        int e = t >> 3, l = t & 7;
        int s = ei[e0 + e], d = ei[NE + e0 + e];
        const float4* hd = (const float4*)(h + (size_t)d * H);
        const float4* hs = (const float4*)(h + (size_t)s * H);
        unsigned short* zr = zs + e * ZB;
        float4 v0 = hd[l * 4 + 0], v1 = hd[l * 4 + 1];
        float4 v2 = hd[l * 4 + 2], v3 = hd[l * 4 + 3];
        uint4 p0 = { pkbf(v0.x, v0.y), pkbf(v0.z, v0.w), pkbf(v1.x, v1.y), pkbf(v1.z, v1.w) };
        uint4 p1 = { pkbf(v2.x, v2.y), pkbf(v2.z, v2.w), pkbf(v3.x, v3.y), pkbf(v3.z, v3.w) };
        *(uint4*)(zr + l * 16) = p0;
        *(uint4*)(zr + l * 16 + 8) = p1;
        float4 w0 = hs[l * 4 + 0], w1 = hs[l * 4 + 1];
        float4 w2 = hs[l * 4 + 2], w3 = hs[l * 4 + 3];
        uint4 q0 = { pkbf(w0.x, w0.y), pkbf(w0.z, w0.w), pkbf(w1.x, w1.y), pkbf(w1.z, w1.w) };
        uint4 q1 = { pkbf(w2.x, w2.y), pkbf(w2.z, w2.w), pkbf(w3.x, w3.y), pkbf(w3.z, w3.w) };
        *(uint4*)(zr + 128 + l * 16) = q0;
        *(uint4*)(zr + 128 + l * 16 + 8) = q1;
    }
    // Geometry + gaussians + edge_attr + pad; 1 thread/edge.
    if (t < EPB) {
        int s = ei[e0 + t], d = ei[NE + e0 + t];
        dst_s[t] = d;
        float rx = x[d * 3 + 0] - x[s * 3 + 0];
        float ry = x[d * 3 + 1] - x[s * 3 + 1];
        float rz = x[d * 3 + 2] - x[s * 3 + 2];
        float d2 = rx * rx + ry * ry + rz * rz;
        float dd = sqrtf(d2 + 1e-8f);
        float inv = frcp(dd + 1.0f);
        relx_s[t][0] = rx * inv;
        relx_s[t][1] = ry * inv;
        relx_s[t][2] = rz * inv;
        const float step = 10.0f / 19.0f;
        const float coeff = -0.5f / (step * step);
        unsigned short* zr = zs + t * ZB;
        #pragma unroll
        for (int g = 0; g < 20; g++) {
            float df = dd - step * (float)g;
            zr[256 + g] = f2bf(__expf(coeff * df * df));
        }
        #pragma unroll
        for (int j = 0; j < 4; j++)
            zr[276 + j] = f2bf(edge_attr[(size_t)(e0 + t) * 4 + j]);
        #pragma unroll
        for (int j = 280; j < ZB; j++) zr[j] = 0;
    }
    __syncthreads();                                               // B

    const int wv = t >> 6, lane = t & 63;
    const int quad = lane >> 4, r16 = lane & 15;
    const int F = wv * 32;

    // Layer 1: (z @ We1)^T -> silu -> m1 (aliases zs; barrier inside)
    layer_mfma<KP1, ZB, true>(zs, w1t, be1, m1, wv, quad, r16);
    __syncthreads();                                               // D

    // Layer 2: mij -> m2 (bf16, aliases upper zs). eij dot fused.
    {
        f32x4 acc[2][2] = {};
        #pragma unroll
        for (int ks = 0; ks < H / 32; ks++) {
            int ko = ks * 32 + quad * 8;
            u16x8 b0 = *(const u16x8*)(m1 + r16 * BB + ko);
            u16x8 b1 = *(const u16x8*)(m1 + (16 + r16) * BB + ko);
            u16x8 a0 = *(const u16x8*)(w2t + (size_t)(F + r16) * H + ko);
            u16x8 a1 = *(const u16x8*)(w2t + (size_t)(F + 16 + r16) * H + ko);
            acc[0][0] = mfma16(a0, b0, acc[0][0]);
            acc[0][1] = mfma16(a0, b1, acc[0][1]);
            acc[1][0] = mfma16(a1, b0, acc[1][0]);
            acc[1][1] = mfma16(a1, b1, acc[1][1]);
        }
        float ep[2] = {0.f, 0.f};
        #pragma unroll
        for (int rt = 0; rt < 2; rt++) {
            int f0 = F + rt * 16 + quad * 4;
            float4 bv = *(const float4*)(be2 + f0);
            float4 wf = *(const float4*)(winf_s + f0);
            #pragma unroll
            for (int ci = 0; ci < 2; ci++) {
                int e = ci * 16 + r16;
                float s0 = silu_f(acc[rt][ci][0] + bv.x);
                float s1 = silu_f(acc[rt][ci][1] + bv.y);
                float s2 = silu_f(acc[rt][ci][2] + bv.z);
                float s3 = silu_f(acc[rt][ci][3] + bv.w);
                ep[ci] += s0 * wf.x + s1 * wf.y + s2 * wf.z + s3 * wf.w;
                uint2 p = { pkbf(s0, s1), pkbf(s2, s3) };
                *(uint2*)(m2 + e * BB + f0) = p;
            }
        }
        #pragma unroll
        for (int ci = 0; ci < 2; ci++) {
            ep[ci] += __shfl_xor(ep[ci], 16, 64);
            ep[ci] += __shfl_xor(ep[ci], 32, 64);
        }
        if (quad == 0) {
            epart[wv][r16] = ep[0];
            epart[wv][16 + r16] = ep[1];
        }
    }
    __syncthreads();                                               // E

    // eij = sigmoid(sum + binf); 32 threads.
    if (t < EPB) {
        float s = epart[0][t] + epart[1][t] + epart[2][t] + epart[3][t] + binf[0];
        eij_s[t] = sigmoid_f(s);
    }

    // Coord layer: silu(mij @ Wx1) . Wx2, never materialized.
    {
        f32x4 acc[2][2] = {};
        #pragma unroll
        for (int ks = 0; ks < H / 32; ks++) {
            int ko = ks * 32 + quad * 8;
            u16x8 b0 = *(const u16x8*)(m2 + r16 * BB + ko);
            u16x8 b1 = *(const u16x8*)(m2 + (16 + r16) * BB + ko);
            u16x8 a0 = *(const u16x8*)(wx1t + (size_t)(F + r16) * H + ko);
            u16x8 a1 = *(const u16x8*)(wx1t + (size_t)(F + 16 + r16) * H + ko);
            acc[0][0] = mfma16(a0, b0, acc[0][0]);
            acc[0][1] = mfma16(a0, b1, acc[0][1]);
            acc[1][0] = mfma16(a1, b0, acc[1][0]);
            acc[1][1] = mfma16(a1, b1, acc[1][1]);
        }
        float xp[2] = {0.f, 0.f};
        #pragma unroll
        for (int rt = 0; rt < 2; rt++) {
            int f0 = F + rt * 16 + quad * 4;
            float4 bv = *(const float4*)(bx1 + f0);
            float4 wf = *(const float4*)(wx2_s + f0);
            #pragma unroll
            for (int ci = 0; ci < 2; ci++) {
                xp[ci] += silu_f(acc[rt][ci][0] + bv.x) * wf.x
                        + silu_f(acc[rt][ci][1] + bv.y) * wf.y
                        + silu_f(acc[rt][ci][2] + bv.z) * wf.z
                        + silu_f(acc[rt][ci][3] + bv.w) * wf.w;
            }
        }
        #pragma unroll
        for (int ci = 0; ci < 2; ci++) {
            xp[ci] += __shfl_xor(xp[ci], 16, 64);
            xp[ci] += __shfl_xor(xp[ci], 32, 64);
        }
        if (quad == 0) {
            xpart[wv][r16] = xp[0];
            xpart[wv][16 + r16] = xp[1];
        }
    }
    __syncthreads();                                               // F

    // Segment sums: contiguous per-edge atomics.
    {
        int k = t & 127, eh = t >> 7;
        for (int e = eh; e < EPB; e += 2) {
            float mv = bf2f(m2[e * BB + k]) * eij_s[e];
            atomicAdd(&mi[(size_t)dst_s[e] * H + k], mv);
        }
        if (t < EPB * 3) {
            int e = t / 3, dim = t % 3;
            float xs = xpart[0][e] + xpart[1][e] + xpart[2][e] + xpart[3][e];
            float xg = tanh_f(xs);
            atomicAdd(&dx[(size_t)dst_s[e] * 3 + dim], relx_s[e][dim] * xg);
        }
    }
}

// ---------------- node kernel (bf16 MFMA) -----------------------------------
// nbuf aliases nzs (dead after n1 K-loop); LDS ~16.9 KB -> high occupancy.
__global__ __launch_bounds__(256, 8) void node_kernel(
    const float* __restrict__ h, const float* __restrict__ x,
    const float* __restrict__ mask,
    const unsigned short* __restrict__ wn1t, const float* __restrict__ bn1,
    const unsigned short* __restrict__ wn2t, const float* __restrict__ bn2,
    float* __restrict__ mi_hout, float* __restrict__ dx_xout)
{
    __shared__ unsigned short nzs[NPB * NZB];   // 8448 shorts; nbuf needs 4352

    unsigned short* nbuf = nzs;

    const int t = threadIdx.x;
    const int n0 = blockIdx.x * NPB;

    {
        int r = t >> 3, l = t & 7;
        int n = n0 + r;
        unsigned short* zr = nzs + r * NZB;
        if (n < NN) {
            const float4* mi4 = (const float4*)(mi_hout + (size_t)n * H);
            const float4* h4  = (const float4*)(h + (size_t)n * H);
            float4 v0 = mi4[l * 4 + 0], v1 = mi4[l * 4 + 1];
            float4 v2 = mi4[l * 4 + 2], v3 = mi4[l * 4 + 3];
            uint4 p0 = { pkbf(v0.x, v0.y), pkbf(v0.z, v0.w), pkbf(v1.x, v1.y), pkbf(v1.z, v1.w) };
            uint4 p1 = { pkbf(v2.x, v2.y), pkbf(v2.z, v2.w), pkbf(v3.x, v3.y), pkbf(v3.z, v3.w) };
            *(uint4*)(zr + l * 16) = p0;
            *(uint4*)(zr + l * 16 + 8) = p1;
            float4 w0 = h4[l * 4 + 0], w1 = h4[l * 4 + 1];
            float4 w2 = h4[l * 4 + 2], w3 = h4[l * 4 + 3];
            uint4 q0 = { pkbf(w0.x, w0.y), pkbf(w0.z, w0.w), pkbf(w1.x, w1.y), pkbf(w1.z, w1.w) };
            uint4 q1 = { pkbf(w2.x, w2.y), pkbf(w2.z, w2.w), pkbf(w3.x, w3.y), pkbf(w3.z, w3.w) };
            *(uint4*)(zr + 128 + l * 16) = q0;
            *(uint4*)(zr + 128 + l * 16 + 8) = q1;
        } else {
            uint4 zf = {0u, 0u, 0u, 0u};
            *(uint4*)(zr + l * 16) = zf;
            *(uint4*)(zr + l * 16 + 8) = zf;
            *(uint4*)(zr + 128 + l * 16) = zf;
            *(uint4*)(zr + 128 + l * 16 + 8) = zf;
        }
    }

    float xo = 0.f;
    int xn = -1, xdim = 0;
    if (t < NPB * 3) {
        int r = t / 3; xdim = t % 3;
        int n = n0 + r;
        if (n < NN) {
            xn = n;
            xo = x[(size_t)n * 3 + xdim] + dx_xout[(size_t)n * 3 + xdim] * mask[n];
        }
    }
    __syncthreads();

    if (xn >= 0) dx_xout[(size_t)xn * 3 + xdim] = xo;

    const int wv = t >> 6, lane = t & 63;
    const int quad = lane >> 4, r16 = lane & 15;

    // n1: silu(nz @ Wn1) -> nbuf (aliases nzs; barrier inside before epilogue)
    layer_mfma<2 * H, NZB, true>(nzs, wn1t, bn1, nbuf, wv, quad, r16);
    __syncthreads();

    {
        f32x4 acc[2][2] = {};
        const int F = wv * 32;
        #pragma unroll
        for (int ks = 0; ks < H / 32; ks++) {
            int ko = ks * 32 + quad * 8;
            u16x8 b0 = *(const u16x8*)(nbuf + r16 * BB + ko);
            u16x8 b1 = *(const u16x8*)(nbuf + (16 + r16) * BB + ko);
            u16x8 a0 = *(const u16x8*)(wn2t + (size_t)(F + r16) * H + ko);
            u16x8 a1 = *(const u16x8*)(wn2t + (size_t)(F + 16 + r16) * H + ko);
            acc[0][0] = mfma16(a0, b0, acc[0][0]);
            acc[0][1] = mfma16(a0, b1, acc[0][1]);
            acc[1][0] = mfma16(a1, b0, acc[1][0]);
            acc[1][1] = mfma16(a1, b1, acc[1][1]);
        }
        #pragma unroll
        for (int rt = 0; rt < 2; rt++) {
            int f0 = F + rt * 16 + quad * 4;
            float4 bv = *(const float4*)(bn2 + f0);
            #pragma unroll
            for (int ci = 0; ci < 2; ci++) {
                int n = n0 + ci * 16 + r16;
                if (n < NN) {
                    float4 hv = *(const float4*)(h + (size_t)n * H + f0);
                    float4 o;
                    o.x = hv.x + acc[rt][ci][0] + bv.x;
                    o.y = hv.y + acc[rt][ci][1] + bv.y;
                    o.z = hv.z + acc[rt][ci][2] + bv.z;
                    o.w = hv.w + acc[rt][ci][3] + bv.w;
                    *(float4*)(mi_hout + (size_t)n * H + f0) = o;
                }
            }
        }
    }
}

extern "C" void kernel_launch(void* const* d_in, const int* in_sizes, int n_in,
                              void* d_out, int out_size, void* d_ws, size_t ws_size,
                              hipStream_t stream) {
    const float* h     = (const float*)d_in[0];
    const float* x     = (const float*)d_in[1];
    const int*   ei    = (const int*)d_in[2];
    const float* mask  = (const float*)d_in[3];
    const float* eattr = (const float*)d_in[4];
    const float* We1   = (const float*)d_in[5];
    const float* be1   = (const float*)d_in[6];
    const float* We2   = (const float*)d_in[7];
    const float* be2   = (const float*)d_in[8];
    const float* Winf  = (const float*)d_in[9];
    const float* binf  = (const float*)d_in[10];
    const float* Wx1   = (const float*)d_in[11];
    const float* bx1   = (const float*)d_in[12];
    const float* Wx2   = (const float*)d_in[13];
    const float* Wn1   = (const float*)d_in[14];
    const float* bn1   = (const float*)d_in[15];
    const float* Wn2   = (const float*)d_in[16];
    const float* bn2   = (const float*)d_in[17];

    float* mi = (float*)d_out;
    float* dx = mi + (size_t)NN * H;

    unsigned short* w1t  = (unsigned short*)d_ws;
    unsigned short* w2t  = w1t + 128 * KP1;
    unsigned short* wx1t = w2t + 128 * H;
    unsigned short* wn1t = wx1t + 128 * H;
    unsigned short* wn2t = wn1t + 128 * 256;

    const int wconv_total = 128 * KP1 + 3 * 128 * H + 128 * 256;
    convert_weights<<<(wconv_total + 255) / 256, 256, 0, stream>>>(
        We1, We2, Wx1, Wn1, Wn2, w1t, w2t, wx1t, wn1t, wn2t);

    const int total4 = (NN * H + NN * 3) / 4;
    zero_kernel<<<(total4 + 255) / 256, 256, 0, stream>>>((float4*)d_out, total4);

    edge_kernel<<<NE / EPB, 256, 0, stream>>>(
        h, x, ei, eattr, w1t, be1, w2t, be2, Winf, binf, wx1t, bx1, Wx2, mi, dx);

    node_kernel<<<(NN + NPB - 1) / NPB, 256, 0, stream>>>(
        h, x, mask, wn1t, bn1, wn2t, bn2, mi, dx);
}